// Round 6
// baseline (236.769 us; speedup 1.0000x reference)
//
#include <hip/hip_runtime.h>
#include <hip/hip_bf16.h>

#define E_DIM 1024
#define NHEAD 16
#define HDIM  64
#define BATCH 4
#define SEQ   2048
#define RQKV  (3 * E_DIM)

typedef __attribute__((ext_vector_type(8))) short bf16x8;
typedef __attribute__((ext_vector_type(4))) float f32x4;
typedef __attribute__((ext_vector_type(16))) float f32x16;

#define SCL2 0.04508422f   // (1/sqrt(E)) * log2(e) = log2(e)/32

static __device__ __forceinline__ unsigned short bits_of(__hip_bfloat16 h) {
    return *reinterpret_cast<unsigned short*>(&h);
}

static __device__ __forceinline__ void gload_lds16(const void* g, void* l) {
    __builtin_amdgcn_global_load_lds(
        (__attribute__((address_space(1))) void*)g,
        (__attribute__((address_space(3))) void*)l, 16, 0, 0);
}

// ---------------- cast fp32 -> bf16, 4 elems/thread ----------------
__global__ void cast_kernel(const float* __restrict__ in,
                            __hip_bfloat16* __restrict__ out, int n4) {
    int i = blockIdx.x * blockDim.x + threadIdx.x;
    if (i < n4) {
        float4 v = reinterpret_cast<const float4*>(in)[i];
        ushort4 u;
        u.x = bits_of(__float2bfloat16(v.x));
        u.y = bits_of(__float2bfloat16(v.y));
        u.z = bits_of(__float2bfloat16(v.z));
        u.w = bits_of(__float2bfloat16(v.w));
        reinterpret_cast<ushort4*>(out)[i] = u;
    }
}

// fused 4-weight cast: blockIdx.y selects the weight
__global__ void cast4_kernel(const float* __restrict__ w0, const float* __restrict__ w1,
                             const float* __restrict__ w2, const float* __restrict__ w3,
                             __hip_bfloat16* __restrict__ o0, __hip_bfloat16* __restrict__ o1,
                             __hip_bfloat16* __restrict__ o2, __hip_bfloat16* __restrict__ o3,
                             int n4) {
    const float* in; __hip_bfloat16* out;
    switch (blockIdx.y) {
        case 0:  in = w0; out = o0; break;
        case 1:  in = w1; out = o1; break;
        case 2:  in = w2; out = o2; break;
        default: in = w3; out = o3; break;
    }
    int i = blockIdx.x * blockDim.x + threadIdx.x;
    if (i < n4) {
        float4 v = reinterpret_cast<const float4*>(in)[i];
        ushort4 u;
        u.x = bits_of(__float2bfloat16(v.x));
        u.y = bits_of(__float2bfloat16(v.y));
        u.z = bits_of(__float2bfloat16(v.z));
        u.w = bits_of(__float2bfloat16(v.w));
        reinterpret_cast<ushort4*>(out)[i] = u;
    }
}

// ---------------- GEMM (m97 structure): C[m][n] = sum_k A[m][k] * Bw[n][k] ----
template<int OUT_BF16>
__global__ __launch_bounds__(256) void gemm_bt(
    const __hip_bfloat16* __restrict__ A,
    const __hip_bfloat16* __restrict__ Bw,
    void* __restrict__ Cv, int M, int N, int K) {
    __shared__ __align__(16) __hip_bfloat16 As[128][32];
    __shared__ __align__(16) __hip_bfloat16 Bs[128][32];

    const int nbx = gridDim.x;
    const int lin = blockIdx.y * nbx + blockIdx.x;
    const int cpx = (nbx * gridDim.y) >> 3;
    const int swz = (lin & 7) * cpx + (lin >> 3);
    const int mBase = (swz / nbx) * 128, nBase = (swz % nbx) * 128;

    const int t = threadIdx.x;
    const int lane = t & 63, w = t >> 6;
    const int wr = (w >> 1) * 64, wc = (w & 1) * 64;
    const int lr = lane & 15, lk = (lane >> 4) * 8;
    const int sr = t >> 2, sc = (t & 3) * 8;
    const int wbase = w * 1024;

    f32x4 acc[4][4];
#pragma unroll
    for (int i = 0; i < 4; ++i)
#pragma unroll
        for (int j = 0; j < 4; ++j) acc[i][j] = (f32x4){0.f, 0.f, 0.f, 0.f};

    for (int kt = 0; kt < K; kt += 32) {
        __syncthreads();
#pragma unroll
        for (int it = 0; it < 2; ++it) {
            gload_lds16(A + (size_t)(mBase + sr + it * 64) * K + kt + sc,
                        (char*)&As[0][0] + wbase + it * 4096);
            gload_lds16(Bw + (size_t)(nBase + sr + it * 64) * K + kt + sc,
                        (char*)&Bs[0][0] + wbase + it * 4096);
        }
        __syncthreads();
        bf16x8 af[4], bfr[4];
#pragma unroll
        for (int i = 0; i < 4; ++i) {
            af[i]  = *reinterpret_cast<const bf16x8*>(&As[wr + i * 16 + lr][lk]);
            bfr[i] = *reinterpret_cast<const bf16x8*>(&Bs[wc + i * 16 + lr][lk]);
        }
#pragma unroll
        for (int i = 0; i < 4; ++i)
#pragma unroll
            for (int j = 0; j < 4; ++j)
                acc[i][j] = __builtin_amdgcn_mfma_f32_16x16x32_bf16(
                    af[i], bfr[j], acc[i][j], 0, 0, 0);
    }

#pragma unroll
    for (int i = 0; i < 4; ++i)
#pragma unroll
        for (int j = 0; j < 4; ++j)
#pragma unroll
            for (int v = 0; v < 4; ++v) {
                const int row = mBase + wr + i * 16 + (lane >> 4) * 4 + v;
                const int col = nBase + wc + j * 16 + lr;
                if (OUT_BF16)
                    ((__hip_bfloat16*)Cv)[(size_t)row * N + col] =
                        __float2bfloat16(acc[i][j][v]);
                else
                    ((float*)Cv)[(size_t)row * N + col] = acc[i][j][v];
            }
}

// ---------------- flash attention, paired causal blocks + key-split ---------
// r4 structure (KVBLK=64, single-buffer, 2 barriers/tile), but each q-pair's
// key range is split across 2 blocks (s=0: first half, s=1: second half incl.
// diagonal) -> 1024 blocks x 4 waves = 16 waves/CU, each block 17 key-tiles.
// Stores UNNORMALIZED partial O^T (fp32) + per-row (m, l) for the combiner.
__global__ __launch_bounds__(256) void attn_kernel(
    const __hip_bfloat16* __restrict__ QKV,   // [B*S][3E], Q|K|V blocks
    float* __restrict__ Pd,                   // [2048 pb][128 q][64 d] fp32
    float* __restrict__ Ml) {                 // [2048 pb][128 q] float2 (m,l)
    __shared__ __align__(16) __hip_bfloat16 Kl[64][64];
    __shared__ __align__(16) __hip_bfloat16 Vt[64][64];

    const int t = threadIdx.x, w = t >> 6, lane = t & 63;
    const int lq = lane & 31, hi = lane >> 5;
    const int x = blockIdx.x & 7, s = blockIdx.x >> 3;
    const int h = blockIdx.y, b = blockIdx.z;

    const size_t rb = (size_t)b * SEQ;
    const __hip_bfloat16* Qg = QKV + rb * RQKV + h * HDIM;
    const __hip_bfloat16* Kg = QKV + rb * RQKV + E_DIM + h * HDIM;
    const __hip_bfloat16* Vg = QKV + rb * RQKV + 2 * E_DIM + h * HDIM;

    const int kst_row  = w * 16 + (lane >> 3);
    const int kst_slot = lane & 7;
    const int vkp = t & 31, vd0 = (t >> 5) * 8;

#pragma unroll 1
    for (int ph = 0; ph < 2; ++ph) {
        const int qb  = (ph == 0) ? x : 15 - x;
        const int qb0 = qb * 128;
        const int qw0 = qb0 + w * 32;
        const int qg  = qw0 + lq;

        bf16x8 aq[4];
#pragma unroll
        for (int d0 = 0; d0 < 4; ++d0)
            aq[d0] = *reinterpret_cast<const bf16x8*>(
                Qg + (size_t)qg * RQKV + d0 * 16 + hi * 8);

        f32x16 oa[2];
#pragma unroll
        for (int m = 0; m < 2; ++m)
#pragma unroll
            for (int r = 0; r < 16; ++r) oa[m][r] = 0.f;
        float m_run = -1e30f, l_run = 0.f;

        // this split's key-tile range: [s*(qb+1), (s+1)*(qb+1)) of 64-key tiles
        const int half = qb + 1;
        const int tEnd = s * half + half;
        for (int ti = s * half; ti < tEnd; ++ti) {
            const int k0 = ti * 64;
            __syncthreads();   // previous tile's (or phase's) LDS reads done

            // --- stage K[64][64] swizzled via pre-swizzled global src ---
#pragma unroll
            for (int i = 0; i < 2; ++i) {
                const int r = kst_row + i * 8;
                const char* src = (const char*)(Kg + (size_t)(k0 + r) * RQKV) +
                                  ((kst_slot * 16) ^ ((r & 7) << 4));
                gload_lds16(src, &Kl[w * 16 + i * 8][0]);
            }
            // --- stage V transposed: Vt[d][k], packed b32 writes ---
            {
                const __hip_bfloat16* vp = Vg + (size_t)(k0 + 2 * vkp) * RQKV + vd0;
                bf16x8 va = *reinterpret_cast<const bf16x8*>(vp);
                bf16x8 vb = *reinterpret_cast<const bf16x8*>(vp + RQKV);
#pragma unroll
                for (int j = 0; j < 8; ++j) {
                    const int d = vd0 + j;
                    const unsigned wbits =
                        ((unsigned)(unsigned short)vb[j] << 16) |
                        (unsigned short)va[j];
                    *reinterpret_cast<unsigned*>(
                        reinterpret_cast<char*>(&Vt[0][0]) + d * 128 +
                        ((vkp * 4) ^ ((d & 7) << 4))) = wbits;
                }
            }
            __syncthreads();

            if (k0 <= qw0 + 31) {
                // --- QK^T (swapped): S^T, lane owns q = lane&31 ---
                f32x16 sc2[2];
#pragma unroll
                for (int tt = 0; tt < 2; ++tt) {
#pragma unroll
                    for (int r = 0; r < 16; ++r) sc2[tt][r] = 0.f;
                    const int kr = tt * 32 + lq;
                    const char* kbase =
                        reinterpret_cast<const char*>(&Kl[0][0]) + kr * 128;
                    const int swz = (kr & 7) << 4;
#pragma unroll
                    for (int d0 = 0; d0 < 4; ++d0) {
                        bf16x8 ak = *reinterpret_cast<const bf16x8*>(
                            kbase + ((d0 * 32 + hi * 16) ^ swz));
                        sc2[tt] = __builtin_amdgcn_mfma_f32_32x32x16_bf16(
                            ak, aq[d0], sc2[tt], 0, 0, 0);
                    }
                }
                // --- causal mask (skipped when tile fully valid) ---
                if (k0 + 63 > qw0) {
#pragma unroll
                    for (int tt = 0; tt < 2; ++tt)
#pragma unroll
                        for (int r = 0; r < 16; ++r) {
                            const int kgl = k0 + tt * 32 +
                                            (r & 3) + 8 * (r >> 2) + 4 * hi;
                            if (kgl > qg) sc2[tt][r] = -1e30f;
                        }
                }
                // --- online softmax with defer-max ---
                float mt = -1e30f;
#pragma unroll
                for (int tt = 0; tt < 2; ++tt)
#pragma unroll
                    for (int r = 0; r < 16; r += 2)
                        mt = fmaxf(mt, fmaxf(sc2[tt][r], sc2[tt][r + 1]));
                mt = fmaxf(mt, __shfl_xor(mt, 32));
                if (!__all(mt <= m_run + 177.445f)) {  // growth > 8 in log2 dom
                    const float mn = fmaxf(m_run, mt);
                    const float corr = exp2f((m_run - mn) * SCL2);
                    l_run *= corr;
                    oa[0] *= corr;
                    oa[1] *= corr;
                    m_run = mn;
                }
                const float nb = -m_run * SCL2;
                float rsum = 0.f;
#pragma unroll
                for (int tt = 0; tt < 2; ++tt) {
                    float s0 = 0.f, s1 = 0.f, s2 = 0.f, s3 = 0.f;
#pragma unroll
                    for (int r = 0; r < 16; r += 4) {
                        float p0 = exp2f(__builtin_fmaf(sc2[tt][r], SCL2, nb));
                        float p1 = exp2f(__builtin_fmaf(sc2[tt][r + 1], SCL2, nb));
                        float p2 = exp2f(__builtin_fmaf(sc2[tt][r + 2], SCL2, nb));
                        float p3 = exp2f(__builtin_fmaf(sc2[tt][r + 3], SCL2, nb));
                        sc2[tt][r] = p0; sc2[tt][r + 1] = p1;
                        sc2[tt][r + 2] = p2; sc2[tt][r + 3] = p3;
                        s0 += p0; s1 += p1; s2 += p2; s3 += p3;
                    }
                    rsum += (s0 + s1) + (s2 + s3);
                }
                rsum += __shfl_xor(rsum, 32);
                l_run += rsum;

                // --- P -> bf16 B-frags via pack + permlane32_swap; PV ---
#pragma unroll
                for (int tt = 0; tt < 2; ++tt)
#pragma unroll
                    for (int sl = 0; sl < 2; ++sl) {
                        const int rbs = sl * 8;
                        const unsigned wA =
                            ((unsigned)bits_of(__float2bfloat16(sc2[tt][rbs + 1])) << 16) |
                            bits_of(__float2bfloat16(sc2[tt][rbs + 0]));
                        const unsigned wB =
                            ((unsigned)bits_of(__float2bfloat16(sc2[tt][rbs + 3])) << 16) |
                            bits_of(__float2bfloat16(sc2[tt][rbs + 2]));
                        const unsigned wC =
                            ((unsigned)bits_of(__float2bfloat16(sc2[tt][rbs + 5])) << 16) |
                            bits_of(__float2bfloat16(sc2[tt][rbs + 4]));
                        const unsigned wD =
                            ((unsigned)bits_of(__float2bfloat16(sc2[tt][rbs + 7])) << 16) |
                            bits_of(__float2bfloat16(sc2[tt][rbs + 6]));
                        const auto pA = __builtin_amdgcn_permlane32_swap(wA, wC, false, false);
                        const auto pB = __builtin_amdgcn_permlane32_swap(wB, wD, false, false);
                        union { unsigned u[4]; bf16x8 v; } pf;
                        pf.u[0] = pA[0]; pf.u[1] = pB[0];
                        pf.u[2] = pA[1]; pf.u[3] = pB[1];
                        const int ks = tt * 2 + sl;
#pragma unroll
                        for (int m = 0; m < 2; ++m) {
                            const int dr = m * 32 + lq;
                            bf16x8 av = *reinterpret_cast<const bf16x8*>(
                                reinterpret_cast<const char*>(&Vt[0][0]) + dr * 128 +
                                ((ks * 32 + hi * 16) ^ ((dr & 7) << 4)));
                            oa[m] = __builtin_amdgcn_mfma_f32_32x32x16_bf16(
                                av, pf.v, oa[m], 0, 0, 0);
                        }
                    }
            }
        }

        // --- epilogue: store unnormalized partial O + (m, l) ---
        const int rowHi = ((b * NHEAD + h) * 16 + qb);
        const int pb = rowHi * 2 + s;
        const int qlocal = w * 32 + lq;
        float* Pr = Pd + (size_t)pb * (128 * 64) + (size_t)qlocal * 64;
#pragma unroll
        for (int m = 0; m < 2; ++m)
#pragma unroll
            for (int q4 = 0; q4 < 4; ++q4) {
                float4 st = {oa[m][q4 * 4 + 0], oa[m][q4 * 4 + 1],
                             oa[m][q4 * 4 + 2], oa[m][q4 * 4 + 3]};
                *reinterpret_cast<float4*>(Pr + m * 32 + q4 * 8 + 4 * hi) = st;
            }
        if (hi == 0)
            reinterpret_cast<float2*>(Ml)[(size_t)pb * 128 + qlocal] =
                make_float2(m_run, l_run);
    }
}

// ---------------- combine the 2 key-splits per q row ----------------
__global__ __launch_bounds__(256) void combine_kernel(
    const float* __restrict__ Pd, const float* __restrict__ Ml,
    __hip_bfloat16* __restrict__ O) {
    const int g = blockIdx.x * 256 + threadIdx.x;  // [0, 131072*8)
    const int row = g >> 3, oct = g & 7;
    const int rowHi = row >> 7, ql = row & 127;

    const float2 ml0 = reinterpret_cast<const float2*>(Ml)[(size_t)rowHi * 256 + ql];
    const float2 ml1 = reinterpret_cast<const float2*>(Ml)[(size_t)rowHi * 256 + 128 + ql];
    const float m = fmaxf(ml0.x, ml1.x);
    float w0 = exp2f((ml0.x - m) * SCL2);
    float w1 = exp2f((ml1.x - m) * SCL2);
    const float inv = 1.f / (ml0.y * w0 + ml1.y * w1);
    w0 *= inv; w1 *= inv;

    const size_t a0 = ((size_t)(rowHi * 2) * 128 + ql) * 64 + oct * 8;
    const size_t a1 = a0 + 128 * 64;
    const float4 p0a = *reinterpret_cast<const float4*>(Pd + a0);
    const float4 p0b = *reinterpret_cast<const float4*>(Pd + a0 + 4);
    const float4 p1a = *reinterpret_cast<const float4*>(Pd + a1);
    const float4 p1b = *reinterpret_cast<const float4*>(Pd + a1 + 4);

    ushort4 u0, u1;
    u0.x = bits_of(__float2bfloat16(p0a.x * w0 + p1a.x * w1));
    u0.y = bits_of(__float2bfloat16(p0a.y * w0 + p1a.y * w1));
    u0.z = bits_of(__float2bfloat16(p0a.z * w0 + p1a.z * w1));
    u0.w = bits_of(__float2bfloat16(p0a.w * w0 + p1a.w * w1));
    u1.x = bits_of(__float2bfloat16(p0b.x * w0 + p1b.x * w1));
    u1.y = bits_of(__float2bfloat16(p0b.y * w0 + p1b.y * w1));
    u1.z = bits_of(__float2bfloat16(p0b.z * w0 + p1b.z * w1));
    u1.w = bits_of(__float2bfloat16(p0b.w * w0 + p1b.w * w1));

    const int b = rowHi >> 8, h = (rowHi >> 4) & 15, qb = rowHi & 15;
    const size_t q = (size_t)qb * 128 + ql;
    __hip_bfloat16* dst = O + ((size_t)b * SEQ + q) * E_DIM + h * HDIM + oct * 8;
    *reinterpret_cast<ushort4*>(dst) = u0;
    *reinterpret_cast<ushort4*>(dst + 4) = u1;
}

// ---------------- launch ----------------
extern "C" void kernel_launch(void* const* d_in, const int* in_sizes, int n_in,
                              void* d_out, int out_size, void* d_ws, size_t ws_size,
                              hipStream_t stream) {
    const float* x  = (const float*)d_in[0];
    const float* wq = (const float*)d_in[1];
    const float* wk = (const float*)d_in[2];
    const float* wv = (const float*)d_in[3];
    const float* wo = (const float*)d_in[4];

    const size_t SZ_X = (size_t)BATCH * SEQ * E_DIM;   // 8388608
    const size_t SZ_W = (size_t)E_DIM * E_DIM;         // 1048576

    // Layout (peak ~138 MB): partials overlap xb/wqkvb, which are dead after
    // the QKV GEMM.
    char* p = (char*)d_ws;
    __hip_bfloat16* wob   = (__hip_bfloat16*)p; p += SZ_W * 2;        // 2.1M
    __hip_bfloat16* QKVb  = (__hip_bfloat16*)p; p += SZ_X * 3 * 2;    // 50.3M
    __hip_bfloat16* attb  = (__hip_bfloat16*)p; p += SZ_X * 2;        // 16.8M
    char* px = p;
    __hip_bfloat16* xb    = (__hip_bfloat16*)p; p += SZ_X * 2;        // 16.8M
    __hip_bfloat16* wqkvb = (__hip_bfloat16*)p; p += 3 * SZ_W * 2;    // 6.3M
    float* Pd = (float*)px;                            // 2048*128*64*4 = 67.1M
    float* Ml = (float*)(px + (size_t)2048 * 128 * 64 * 4);           // 2.1M

    cast_kernel<<<(int)(SZ_X / 4 / 256), 256, 0, stream>>>(x, xb, (int)(SZ_X / 4));
    cast4_kernel<<<dim3((unsigned)(SZ_W / 4 / 256), 4), 256, 0, stream>>>(
        wq, wk, wv, wo, wqkvb, wqkvb + SZ_W, wqkvb + 2 * SZ_W, wob,
        (int)(SZ_W / 4));

    const int M = BATCH * SEQ;  // 8192
    gemm_bt<1><<<dim3(RQKV / 128, M / 128), 256, 0, stream>>>(
        xb, wqkvb, QKVb, M, RQKV, E_DIM);

    // 1024 blocks: (8 q-pairs x 2 key-splits, H, B)
    attn_kernel<<<dim3(16, NHEAD, BATCH), 256, 0, stream>>>(QKVb, Pd, Ml);
    combine_kernel<<<4096, 256, 0, stream>>>(Pd, Ml, attb);

    gemm_bt<0><<<dim3(E_DIM / 128, M / 128), 256, 0, stream>>>(
        attb, wob, d_out, M, E_DIM, E_DIM);
}

// Round 7
// 214.377 us; speedup vs baseline: 1.1045x; 1.1045x over previous
//
#include <hip/hip_runtime.h>
#include <hip/hip_bf16.h>

#define E_DIM 1024
#define NHEAD 16
#define HDIM  64
#define BATCH 4
#define SEQ   2048
#define RQKV  (3 * E_DIM)

typedef __attribute__((ext_vector_type(8))) short bf16x8;
typedef __attribute__((ext_vector_type(4))) float f32x4;
typedef __attribute__((ext_vector_type(16))) float f32x16;

#define SCL2 0.04508422f   // (1/sqrt(E)) * log2(e) = log2(e)/32

static __device__ __forceinline__ unsigned short bits_of(__hip_bfloat16 h) {
    return *reinterpret_cast<unsigned short*>(&h);
}

static __device__ __forceinline__ void gload_lds16(const void* g, void* l) {
    __builtin_amdgcn_global_load_lds(
        (__attribute__((address_space(1))) void*)g,
        (__attribute__((address_space(3))) void*)l, 16, 0, 0);
}

// ---------------- cast fp32 -> bf16, 4 elems/thread ----------------
__global__ void cast_kernel(const float* __restrict__ in,
                            __hip_bfloat16* __restrict__ out, int n4) {
    int i = blockIdx.x * blockDim.x + threadIdx.x;
    if (i < n4) {
        float4 v = reinterpret_cast<const float4*>(in)[i];
        ushort4 u;
        u.x = bits_of(__float2bfloat16(v.x));
        u.y = bits_of(__float2bfloat16(v.y));
        u.z = bits_of(__float2bfloat16(v.z));
        u.w = bits_of(__float2bfloat16(v.w));
        reinterpret_cast<ushort4*>(out)[i] = u;
    }
}

// fused 4-weight cast: blockIdx.y selects the weight
__global__ void cast4_kernel(const float* __restrict__ w0, const float* __restrict__ w1,
                             const float* __restrict__ w2, const float* __restrict__ w3,
                             __hip_bfloat16* __restrict__ o0, __hip_bfloat16* __restrict__ o1,
                             __hip_bfloat16* __restrict__ o2, __hip_bfloat16* __restrict__ o3,
                             int n4) {
    const float* in; __hip_bfloat16* out;
    switch (blockIdx.y) {
        case 0:  in = w0; out = o0; break;
        case 1:  in = w1; out = o1; break;
        case 2:  in = w2; out = o2; break;
        default: in = w3; out = o3; break;
    }
    int i = blockIdx.x * blockDim.x + threadIdx.x;
    if (i < n4) {
        float4 v = reinterpret_cast<const float4*>(in)[i];
        ushort4 u;
        u.x = bits_of(__float2bfloat16(v.x));
        u.y = bits_of(__float2bfloat16(v.y));
        u.z = bits_of(__float2bfloat16(v.z));
        u.w = bits_of(__float2bfloat16(v.w));
        reinterpret_cast<ushort4*>(out)[i] = u;
    }
}

// ---------------- GEMM (m97 structure): C[m][n] = sum_k A[m][k] * Bw[n][k] ----
template<int OUT_BF16>
__global__ __launch_bounds__(256) void gemm_bt(
    const __hip_bfloat16* __restrict__ A,
    const __hip_bfloat16* __restrict__ Bw,
    void* __restrict__ Cv, int M, int N, int K) {
    __shared__ __align__(16) __hip_bfloat16 As[128][32];
    __shared__ __align__(16) __hip_bfloat16 Bs[128][32];

    const int nbx = gridDim.x;
    const int lin = blockIdx.y * nbx + blockIdx.x;
    const int cpx = (nbx * gridDim.y) >> 3;
    const int swz = (lin & 7) * cpx + (lin >> 3);
    const int mBase = (swz / nbx) * 128, nBase = (swz % nbx) * 128;

    const int t = threadIdx.x;
    const int lane = t & 63, w = t >> 6;
    const int wr = (w >> 1) * 64, wc = (w & 1) * 64;
    const int lr = lane & 15, lk = (lane >> 4) * 8;
    const int sr = t >> 2, sc = (t & 3) * 8;
    const int wbase = w * 1024;

    f32x4 acc[4][4];
#pragma unroll
    for (int i = 0; i < 4; ++i)
#pragma unroll
        for (int j = 0; j < 4; ++j) acc[i][j] = (f32x4){0.f, 0.f, 0.f, 0.f};

    for (int kt = 0; kt < K; kt += 32) {
        __syncthreads();
#pragma unroll
        for (int it = 0; it < 2; ++it) {
            gload_lds16(A + (size_t)(mBase + sr + it * 64) * K + kt + sc,
                        (char*)&As[0][0] + wbase + it * 4096);
            gload_lds16(Bw + (size_t)(nBase + sr + it * 64) * K + kt + sc,
                        (char*)&Bs[0][0] + wbase + it * 4096);
        }
        __syncthreads();
        bf16x8 af[4], bfr[4];
#pragma unroll
        for (int i = 0; i < 4; ++i) {
            af[i]  = *reinterpret_cast<const bf16x8*>(&As[wr + i * 16 + lr][lk]);
            bfr[i] = *reinterpret_cast<const bf16x8*>(&Bs[wc + i * 16 + lr][lk]);
        }
#pragma unroll
        for (int i = 0; i < 4; ++i)
#pragma unroll
            for (int j = 0; j < 4; ++j)
                acc[i][j] = __builtin_amdgcn_mfma_f32_16x16x32_bf16(
                    af[i], bfr[j], acc[i][j], 0, 0, 0);
    }

#pragma unroll
    for (int i = 0; i < 4; ++i)
#pragma unroll
        for (int j = 0; j < 4; ++j)
#pragma unroll
            for (int v = 0; v < 4; ++v) {
                const int row = mBase + wr + i * 16 + (lane >> 4) * 4 + v;
                const int col = nBase + wc + j * 16 + lr;
                if (OUT_BF16)
                    ((__hip_bfloat16*)Cv)[(size_t)row * N + col] =
                        __float2bfloat16(acc[i][j][v]);
                else
                    ((float*)Cv)[(size_t)row * N + col] = acc[i][j][v];
            }
}

// ---------------- flash attention, paired causal blocks + async-STAGE -------
// r4 structure: 4 waves x 32 q-rows, KVBLK=64, paired q-tiles (block x does
// qb=x then qb=15-x -> uniform 34 tiles). T14 async-STAGE split: tile t+1's
// K/V are loaded to REGISTERS right after the barrier and fly during tile t's
// compute; regs are written to (single-buffered) LDS after the next barrier.
// No exposed global-load latency; same 2 barriers/tile as r4.
__global__ __launch_bounds__(256) void attn_kernel(
    const __hip_bfloat16* __restrict__ QKV,   // [B*S][3E], Q|K|V blocks
    __hip_bfloat16* __restrict__ O) {         // [B*S][E]
    __shared__ __align__(16) __hip_bfloat16 Kl[64][64];
    __shared__ __align__(16) __hip_bfloat16 Vt[64][64];

    const int t = threadIdx.x, w = t >> 6, lane = t & 63;
    const int lq = lane & 31, hi = lane >> 5;
    const int x = blockIdx.x;
    const int h = blockIdx.y, b = blockIdx.z;

    const size_t rb = (size_t)b * SEQ;
    const __hip_bfloat16* Qg = QKV + rb * RQKV + h * HDIM;
    const __hip_bfloat16* Kg = QKV + rb * RQKV + E_DIM + h * HDIM;
    const __hip_bfloat16* Vg = QKV + rb * RQKV + 2 * E_DIM + h * HDIM;

    // K staging: lane covers rows w*16 + i*8 + (lane>>3), 16B col (lane&7)*16
    const int krow0 = w * 16 + (lane >> 3);
    const int kcolb = (lane & 7) * 16;          // source col in bytes (linear)
    const int vkp = t & 31, vd0 = (t >> 5) * 8; // V staging assignment

#pragma unroll 1
    for (int ph = 0; ph < 2; ++ph) {
        const int qb  = (ph == 0) ? x : 15 - x;
        const int qb0 = qb * 128;
        const int qw0 = qb0 + w * 32;
        const int qg  = qw0 + lq;

        bf16x8 aq[4];
#pragma unroll
        for (int d0 = 0; d0 < 4; ++d0)
            aq[d0] = *reinterpret_cast<const bf16x8*>(
                Qg + (size_t)qg * RQKV + d0 * 16 + hi * 8);

        f32x16 oa[2];
#pragma unroll
        for (int m = 0; m < 2; ++m)
#pragma unroll
            for (int r = 0; r < 16; ++r) oa[m][r] = 0.f;
        float m_run = -1e30f, l_run = 0.f;

        const int NT = qb * 2 + 2;

        // ---- prologue: load tile 0 into regs ----
        bf16x8 kreg[2], va, vb;
#pragma unroll
        for (int i = 0; i < 2; ++i)
            kreg[i] = *reinterpret_cast<const bf16x8*>(
                (const char*)(Kg + (size_t)(krow0 + i * 8) * RQKV) + kcolb);
        {
            const __hip_bfloat16* vp = Vg + (size_t)(2 * vkp) * RQKV + vd0;
            va = *reinterpret_cast<const bf16x8*>(vp);
            vb = *reinterpret_cast<const bf16x8*>(vp + RQKV);
        }

        for (int kt = 0; kt < NT; ++kt) {
            const int k0 = kt * 64;

            // ---- write staged regs -> LDS (K swizzled dest, V transposed) ----
#pragma unroll
            for (int i = 0; i < 2; ++i) {
                const int r = krow0 + i * 8;
                *reinterpret_cast<bf16x8*>(
                    reinterpret_cast<char*>(&Kl[0][0]) + r * 128 +
                    (kcolb ^ ((r & 7) << 4))) = kreg[i];
            }
#pragma unroll
            for (int j = 0; j < 8; ++j) {
                const int d = vd0 + j;
                const unsigned wbits =
                    ((unsigned)(unsigned short)vb[j] << 16) |
                    (unsigned short)va[j];
                *reinterpret_cast<unsigned*>(
                    reinterpret_cast<char*>(&Vt[0][0]) + d * 128 +
                    ((vkp * 4) ^ ((d & 7) << 4))) = wbits;
            }
            __syncthreads();   // staging visible to all waves

            // ---- issue tile kt+1 loads -> regs (fly during compute) ----
            if (kt + 1 < NT) {
                const int k0n = k0 + 64;
#pragma unroll
                for (int i = 0; i < 2; ++i)
                    kreg[i] = *reinterpret_cast<const bf16x8*>(
                        (const char*)(Kg + (size_t)(k0n + krow0 + i * 8) * RQKV) +
                        kcolb);
                const __hip_bfloat16* vp =
                    Vg + (size_t)(k0n + 2 * vkp) * RQKV + vd0;
                va = *reinterpret_cast<const bf16x8*>(vp);
                vb = *reinterpret_cast<const bf16x8*>(vp + RQKV);
            }

            if (k0 <= qw0 + 31) {
                // --- QK^T (swapped): S^T, lane owns q = lane&31 ---
                f32x16 sc2[2];
#pragma unroll
                for (int tt = 0; tt < 2; ++tt) {
#pragma unroll
                    for (int r = 0; r < 16; ++r) sc2[tt][r] = 0.f;
                    const int kr = tt * 32 + lq;
                    const char* kbase =
                        reinterpret_cast<const char*>(&Kl[0][0]) + kr * 128;
                    const int swz = (kr & 7) << 4;
#pragma unroll
                    for (int d0 = 0; d0 < 4; ++d0) {
                        bf16x8 ak = *reinterpret_cast<const bf16x8*>(
                            kbase + ((d0 * 32 + hi * 16) ^ swz));
                        sc2[tt] = __builtin_amdgcn_mfma_f32_32x32x16_bf16(
                            ak, aq[d0], sc2[tt], 0, 0, 0);
                    }
                }
                // --- causal mask (skipped when tile fully valid) ---
                if (k0 + 63 > qw0) {
#pragma unroll
                    for (int tt = 0; tt < 2; ++tt)
#pragma unroll
                        for (int r = 0; r < 16; ++r) {
                            const int kgl = k0 + tt * 32 +
                                            (r & 3) + 8 * (r >> 2) + 4 * hi;
                            if (kgl > qg) sc2[tt][r] = -1e30f;
                        }
                }
                // --- online softmax with defer-max ---
                float mt = -1e30f;
#pragma unroll
                for (int tt = 0; tt < 2; ++tt)
#pragma unroll
                    for (int r = 0; r < 16; r += 2)
                        mt = fmaxf(mt, fmaxf(sc2[tt][r], sc2[tt][r + 1]));
                mt = fmaxf(mt, __shfl_xor(mt, 32));
                if (!__all(mt <= m_run + 177.445f)) {  // growth > 8 in log2 dom
                    const float mn = fmaxf(m_run, mt);
                    const float corr = exp2f((m_run - mn) * SCL2);
                    l_run *= corr;
                    oa[0] *= corr;
                    oa[1] *= corr;
                    m_run = mn;
                }
                const float nb = -m_run * SCL2;
                float rsum = 0.f;
#pragma unroll
                for (int tt = 0; tt < 2; ++tt) {
                    float s0 = 0.f, s1 = 0.f, s2 = 0.f, s3 = 0.f;
#pragma unroll
                    for (int r = 0; r < 16; r += 4) {
                        float p0 = exp2f(__builtin_fmaf(sc2[tt][r], SCL2, nb));
                        float p1 = exp2f(__builtin_fmaf(sc2[tt][r + 1], SCL2, nb));
                        float p2 = exp2f(__builtin_fmaf(sc2[tt][r + 2], SCL2, nb));
                        float p3 = exp2f(__builtin_fmaf(sc2[tt][r + 3], SCL2, nb));
                        sc2[tt][r] = p0; sc2[tt][r + 1] = p1;
                        sc2[tt][r + 2] = p2; sc2[tt][r + 3] = p3;
                        s0 += p0; s1 += p1; s2 += p2; s3 += p3;
                    }
                    rsum += (s0 + s1) + (s2 + s3);
                }
                rsum += __shfl_xor(rsum, 32);
                l_run += rsum;

                // --- P -> bf16 B-frags via pack + permlane32_swap; PV ---
#pragma unroll
                for (int tt = 0; tt < 2; ++tt)
#pragma unroll
                    for (int sl = 0; sl < 2; ++sl) {
                        const int rbs = sl * 8;
                        const unsigned wA =
                            ((unsigned)bits_of(__float2bfloat16(sc2[tt][rbs + 1])) << 16) |
                            bits_of(__float2bfloat16(sc2[tt][rbs + 0]));
                        const unsigned wB =
                            ((unsigned)bits_of(__float2bfloat16(sc2[tt][rbs + 3])) << 16) |
                            bits_of(__float2bfloat16(sc2[tt][rbs + 2]));
                        const unsigned wC =
                            ((unsigned)bits_of(__float2bfloat16(sc2[tt][rbs + 5])) << 16) |
                            bits_of(__float2bfloat16(sc2[tt][rbs + 4]));
                        const unsigned wD =
                            ((unsigned)bits_of(__float2bfloat16(sc2[tt][rbs + 7])) << 16) |
                            bits_of(__float2bfloat16(sc2[tt][rbs + 6]));
                        const auto pA = __builtin_amdgcn_permlane32_swap(wA, wC, false, false);
                        const auto pB = __builtin_amdgcn_permlane32_swap(wB, wD, false, false);
                        union { unsigned u[4]; bf16x8 v; } pf;
                        pf.u[0] = pA[0]; pf.u[1] = pB[0];
                        pf.u[2] = pA[1]; pf.u[3] = pB[1];
                        const int ks = tt * 2 + sl;
#pragma unroll
                        for (int m = 0; m < 2; ++m) {
                            const int dr = m * 32 + lq;
                            bf16x8 av = *reinterpret_cast<const bf16x8*>(
                                reinterpret_cast<const char*>(&Vt[0][0]) + dr * 128 +
                                ((ks * 32 + hi * 16) ^ ((dr & 7) << 4)));
                            oa[m] = __builtin_amdgcn_mfma_f32_32x32x16_bf16(
                                av, pf.v, oa[m], 0, 0, 0);
                        }
                    }
            }
            __syncthreads();   // compute reads done; next write may overwrite
        }

        // --- epilogue for this phase: normalize, pack, store bf16 ---
        const float inv = 1.f / l_run;
        __hip_bfloat16* Orow = O + (rb + qg) * E_DIM + h * HDIM;
#pragma unroll
        for (int m = 0; m < 2; ++m)
#pragma unroll
            for (int q4 = 0; q4 < 4; ++q4) {
                ushort4 pk;
                pk.x = bits_of(__float2bfloat16(oa[m][q4 * 4 + 0] * inv));
                pk.y = bits_of(__float2bfloat16(oa[m][q4 * 4 + 1] * inv));
                pk.z = bits_of(__float2bfloat16(oa[m][q4 * 4 + 2] * inv));
                pk.w = bits_of(__float2bfloat16(oa[m][q4 * 4 + 3] * inv));
                *reinterpret_cast<ushort4*>(Orow + m * 32 + q4 * 8 + 4 * hi) = pk;
            }
    }
}

// ---------------- launch ----------------
extern "C" void kernel_launch(void* const* d_in, const int* in_sizes, int n_in,
                              void* d_out, int out_size, void* d_ws, size_t ws_size,
                              hipStream_t stream) {
    const float* x  = (const float*)d_in[0];
    const float* wq = (const float*)d_in[1];
    const float* wk = (const float*)d_in[2];
    const float* wv = (const float*)d_in[3];
    const float* wo = (const float*)d_in[4];

    const size_t SZ_X = (size_t)BATCH * SEQ * E_DIM;   // 8388608
    const size_t SZ_W = (size_t)E_DIM * E_DIM;         // 1048576

    char* p = (char*)d_ws;
    __hip_bfloat16* xb    = (__hip_bfloat16*)p; p += SZ_X * 2;
    __hip_bfloat16* wqkvb = (__hip_bfloat16*)p; p += 3 * SZ_W * 2;   // [3E][E]
    __hip_bfloat16* wob   = (__hip_bfloat16*)p; p += SZ_W * 2;
    __hip_bfloat16* QKVb  = (__hip_bfloat16*)p; p += SZ_X * 3 * 2;   // [M][3E]
    __hip_bfloat16* attb  = (__hip_bfloat16*)p; p += SZ_X * 2;

    cast_kernel<<<(int)(SZ_X / 4 / 256), 256, 0, stream>>>(x, xb, (int)(SZ_X / 4));
    cast4_kernel<<<dim3((unsigned)(SZ_W / 4 / 256), 4), 256, 0, stream>>>(
        wq, wk, wv, wo, wqkvb, wqkvb + SZ_W, wqkvb + 2 * SZ_W, wob,
        (int)(SZ_W / 4));

    const int M = BATCH * SEQ;  // 8192
    gemm_bt<1><<<dim3(RQKV / 128, M / 128), 256, 0, stream>>>(
        xb, wqkvb, QKVb, M, RQKV, E_DIM);

    attn_kernel<<<dim3(8, NHEAD, BATCH), 256, 0, stream>>>(QKVb, attb);

    gemm_bt<0><<<dim3(E_DIM / 128, M / 128), 256, 0, stream>>>(
        attb, wob, d_out, M, E_DIM, E_DIM);
}